// Round 4
// baseline (1607.205 us; speedup 1.0000x reference)
//
#include <hip/hip_runtime.h>

#define NN 100000
#define NE 1600000
#define D 128
#define LN_EPS 1e-5f

__device__ __forceinline__ float f4_get(const float4& v, int kk) {
    return kk == 0 ? v.x : kk == 1 ? v.y : kk == 2 ? v.z : v.w;
}

// K1: LayerNorm + ReLU, one wave per node
__global__ __launch_bounds__(256) void k_ln(const float* __restrict__ x,
                                            const float* __restrict__ gamma,
                                            const float* __restrict__ beta,
                                            float* __restrict__ a) {
    int wave = threadIdx.x >> 6, lane = threadIdx.x & 63;
    int node = blockIdx.x * 4 + wave;
    if (node >= NN) return;
    const float* xr = x + (size_t)node * D;
    float v0 = xr[lane], v1 = xr[lane + 64];
    float s = v0 + v1;
    #pragma unroll
    for (int o = 32; o; o >>= 1) s += __shfl_xor(s, o);
    float mu = s * (1.f / 128.f);
    float d0 = v0 - mu, d1 = v1 - mu;
    float q = d0 * d0 + d1 * d1;
    #pragma unroll
    for (int o = 32; o; o >>= 1) q += __shfl_xor(q, o);
    float rs = rsqrtf(q * (1.f / 128.f) + LN_EPS);
    float a0 = fmaxf(fmaf(d0 * rs, gamma[lane], beta[lane]), 0.f);
    float a1 = fmaxf(fmaf(d1 * rs, gamma[lane + 64], beta[lane + 64]), 0.f);
    float* ar = a + (size_t)node * D;
    ar[lane] = a0;
    ar[lane + 64] = a1;
}

// K2: h = a @ W, in-place on a. Block = 256 threads = 32 rows x 128 cols tile.
// Thread t: rows mBase..mBase+3 (mBase=(t>>5)*4), cols cBase..cBase+3 (cBase=(t&31)*4).
__global__ __launch_bounds__(256) void k_gemm(float* __restrict__ a,
                                              const float* __restrict__ W) {
    int t = threadIdx.x;
    int mBase = (t >> 5) * 4;
    int cBase = (t & 31) * 4;
    size_t rowBase = (size_t)blockIdx.x * 32;
    const float* A0 = a + (rowBase + mBase) * D;
    const float* Wp = W + cBase;
    float4 acc[4];
    #pragma unroll
    for (int i = 0; i < 4; ++i) acc[i] = make_float4(0.f, 0.f, 0.f, 0.f);

    for (int k = 0; k < D; k += 4) {
        float4 am[4];
        #pragma unroll
        for (int i = 0; i < 4; ++i)
            am[i] = *(const float4*)(A0 + (size_t)i * D + k);
        #pragma unroll
        for (int kk = 0; kk < 4; ++kk) {
            float4 w4 = *(const float4*)(Wp + (size_t)(k + kk) * D);
            #pragma unroll
            for (int i = 0; i < 4; ++i) {
                float av = f4_get(am[i], kk);
                acc[i].x = fmaf(av, w4.x, acc[i].x);
                acc[i].y = fmaf(av, w4.y, acc[i].y);
                acc[i].z = fmaf(av, w4.z, acc[i].z);
                acc[i].w = fmaf(av, w4.w, acc[i].w);
            }
        }
    }
    __syncthreads();  // drain all tile reads before in-place overwrite
    #pragma unroll
    for (int i = 0; i < 4; ++i)
        *(float4*)(a + (rowBase + mBase + i) * D + cBase) = acc[i];
}

// K3: degree histogram over targets (col)
__global__ __launch_bounds__(256) void k_deg(const int* __restrict__ col,
                                             unsigned* __restrict__ deg) {
    int e = blockIdx.x * 256 + threadIdx.x;
    if (e < NE) atomicAdd(&deg[col[e]], 1u);
}

// K4: dinv = rsqrt(deg + 1)   (+1 = self loop; always > 0)
__global__ __launch_bounds__(256) void k_dinv(const unsigned* __restrict__ deg,
                                              float* __restrict__ dinv) {
    int i = blockIdx.x * 256 + threadIdx.x;
    if (i < NN) dinv[i] = rsqrtf((float)(deg[i] + 1u));
}

// K5: out = h * dinv^2 (self loop) + bias  — writes every element (d_out poisoned)
__global__ __launch_bounds__(256) void k_self(const float* __restrict__ h,
                                              const float* __restrict__ dinv,
                                              const float* __restrict__ bias,
                                              float* __restrict__ out) {
    size_t i = (size_t)blockIdx.x * 256 + threadIdx.x;  // over NN*32 float4 slots
    if (i >= (size_t)NN * 32) return;
    int node = (int)(i >> 5);
    int c = ((int)i & 31) * 4;
    float sc = dinv[node];
    sc = sc * sc;
    float4 hv = *(const float4*)(h + (size_t)node * D + c);
    float4 bv = *(const float4*)(bias + c);
    float4 o;
    o.x = fmaf(hv.x, sc, bv.x);
    o.y = fmaf(hv.y, sc, bv.y);
    o.z = fmaf(hv.z, sc, bv.z);
    o.w = fmaf(hv.w, sc, bv.w);
    *(float4*)(out + (size_t)node * D + c) = o;
}

// K6: edge scatter — one wave per edge, lane owns features 2*lane, 2*lane+1
__global__ __launch_bounds__(256) void k_edge(const int* __restrict__ row,
                                              const int* __restrict__ col,
                                              const float* __restrict__ h,
                                              const float* __restrict__ dinv,
                                              float* __restrict__ out) {
    int wave = threadIdx.x >> 6, lane = threadIdx.x & 63;
    int e = blockIdx.x * 4 + wave;
    if (e >= NE) return;
    int r = row[e], c = col[e];
    float nrm = dinv[r] * dinv[c];
    float2 hv = *(const float2*)(h + (size_t)r * D + lane * 2);
    float* op = out + (size_t)c * D + lane * 2;
    atomicAdd(op, hv.x * nrm);
    atomicAdd(op + 1, hv.y * nrm);
}

extern "C" void kernel_launch(void* const* d_in, const int* in_sizes, int n_in,
                              void* d_out, int out_size, void* d_ws, size_t ws_size,
                              hipStream_t stream) {
    const float* x     = (const float*)d_in[0];
    const int*   ei    = (const int*)d_in[1];     // [2, NE] flat: row then col
    const float* gamma = (const float*)d_in[2];
    const float* beta  = (const float*)d_in[3];
    const float* W     = (const float*)d_in[4];
    const float* bias  = (const float*)d_in[5];
    float* out = (float*)d_out;

    const int* row = ei;
    const int* col = ei + NE;

    char* ws = (char*)d_ws;
    float*    a    = (float*)ws;                         // NN*D floats = 51.2 MB (a, then h in-place)
    unsigned* deg  = (unsigned*)(ws + (size_t)NN * D * 4);      // +51,200,000
    float*    dinv = (float*)(ws + (size_t)NN * D * 4 + 400000); // +51,600,000

    hipMemsetAsync(deg, 0, NN * sizeof(unsigned), stream);

    k_ln  <<<NN / 4,        256, 0, stream>>>(x, gamma, beta, a);
    k_gemm<<<NN / 32,       256, 0, stream>>>(a, W);
    k_deg <<<NE / 256,      256, 0, stream>>>(col, deg);
    k_dinv<<<(NN + 255)/256,256, 0, stream>>>(deg, dinv);
    k_self<<<NN * 32 / 256, 256, 0, stream>>>(a, dinv, bias, out);
    k_edge<<<NE / 4,        256, 0, stream>>>(row, col, a, dinv, out);
}

// Round 5
// 545.008 us; speedup vs baseline: 2.9490x; 2.9490x over previous
//
#include <hip/hip_runtime.h>

#define NN 100000
#define NE 1600000
#define D 128
#define LN_EPS 1e-5f

// ---- workspace layout in 4-byte words ----
#define WS_HS      0           // NN*D floats (a, then hs=relu(ln)@W * dinv, in place)
#define WS_DEG     12800000    // NN u32
#define WS_DINV    12900000    // NN f32
#define WS_ROWPTR  13000000    // NN+1 u32
#define WS_CURSOR  13100004    // NN u32
#define WS_BSUM    13200004    // 391 u32
#define WS_BOFF    13200404    // 391 u32
#define WS_SRC     13201000    // NE u32   (ends at 14,801,000 words = 59.2 MB)
#define NBLK_SCAN  391         // ceil(NN/256)

__device__ __forceinline__ float f4_get(const float4& v, int kk) {
    return kk == 0 ? v.x : kk == 1 ? v.y : kk == 2 ? v.z : v.w;
}

// K1: LayerNorm + ReLU, one wave per node
__global__ __launch_bounds__(256) void k_ln(const float* __restrict__ x,
                                            const float* __restrict__ gamma,
                                            const float* __restrict__ beta,
                                            float* __restrict__ a) {
    int wave = threadIdx.x >> 6, lane = threadIdx.x & 63;
    int node = blockIdx.x * 4 + wave;
    if (node >= NN) return;
    const float* xr = x + (size_t)node * D;
    float v0 = xr[lane], v1 = xr[lane + 64];
    float s = v0 + v1;
    #pragma unroll
    for (int o = 32; o; o >>= 1) s += __shfl_xor(s, o);
    float mu = s * (1.f / 128.f);
    float d0 = v0 - mu, d1 = v1 - mu;
    float q = d0 * d0 + d1 * d1;
    #pragma unroll
    for (int o = 32; o; o >>= 1) q += __shfl_xor(q, o);
    float rs = rsqrtf(q * (1.f / 128.f) + LN_EPS);
    float a0 = fmaxf(fmaf(d0 * rs, gamma[lane], beta[lane]), 0.f);
    float a1 = fmaxf(fmaf(d1 * rs, gamma[lane + 64], beta[lane + 64]), 0.f);
    float* ar = a + (size_t)node * D;
    ar[lane] = a0;
    ar[lane + 64] = a1;
}

// K2: hs = (a @ W) * dinv[row], in-place on a. 32 rows x 128 cols per block.
__global__ __launch_bounds__(256) void k_gemm(float* __restrict__ a,
                                              const float* __restrict__ W,
                                              const float* __restrict__ dinv) {
    int t = threadIdx.x;
    int mBase = (t >> 5) * 4;
    int cBase = (t & 31) * 4;
    size_t rowBase = (size_t)blockIdx.x * 32;
    const float* A0 = a + (rowBase + mBase) * D;
    const float* Wp = W + cBase;
    float4 acc[4];
    #pragma unroll
    for (int i = 0; i < 4; ++i) acc[i] = make_float4(0.f, 0.f, 0.f, 0.f);

    for (int k = 0; k < D; k += 4) {
        float4 am[4];
        #pragma unroll
        for (int i = 0; i < 4; ++i)
            am[i] = *(const float4*)(A0 + (size_t)i * D + k);
        #pragma unroll
        for (int kk = 0; kk < 4; ++kk) {
            float4 w4 = *(const float4*)(Wp + (size_t)(k + kk) * D);
            #pragma unroll
            for (int i = 0; i < 4; ++i) {
                float av = f4_get(am[i], kk);
                acc[i].x = fmaf(av, w4.x, acc[i].x);
                acc[i].y = fmaf(av, w4.y, acc[i].y);
                acc[i].z = fmaf(av, w4.z, acc[i].z);
                acc[i].w = fmaf(av, w4.w, acc[i].w);
            }
        }
    }
    __syncthreads();  // drain all tile reads before in-place overwrite
    #pragma unroll
    for (int i = 0; i < 4; ++i) {
        float dv = dinv[rowBase + mBase + i];
        float4 o;
        o.x = acc[i].x * dv; o.y = acc[i].y * dv;
        o.z = acc[i].z * dv; o.w = acc[i].w * dv;
        *(float4*)(a + (rowBase + mBase + i) * D + cBase) = o;
    }
}

// K3: degree histogram over targets (col)
__global__ __launch_bounds__(256) void k_deg(const int* __restrict__ col,
                                             unsigned* __restrict__ deg) {
    int e = blockIdx.x * 256 + threadIdx.x;
    if (e < NE) atomicAdd(&deg[col[e]], 1u);
}

// K4: dinv = rsqrt(deg + 1)
__global__ __launch_bounds__(256) void k_dinv(const unsigned* __restrict__ deg,
                                              float* __restrict__ dinv) {
    int i = blockIdx.x * 256 + threadIdx.x;
    if (i < NN) dinv[i] = rsqrtf((float)(deg[i] + 1u));
}

// Scan phase 1: per-256-block sums of deg
__global__ __launch_bounds__(256) void k_sumblk(const unsigned* __restrict__ deg,
                                                unsigned* __restrict__ bsum) {
    int i = blockIdx.x * 256 + threadIdx.x;
    unsigned v = (i < NN) ? deg[i] : 0u;
    #pragma unroll
    for (int o = 32; o; o >>= 1) v += __shfl_xor(v, o);
    __shared__ unsigned sm[4];
    if ((threadIdx.x & 63) == 0) sm[threadIdx.x >> 6] = v;
    __syncthreads();
    if (threadIdx.x == 0)
        bsum[blockIdx.x] = sm[0] + sm[1] + sm[2] + sm[3];
}

// Scan phase 2: exclusive scan of bsum (NBLK_SCAN entries), one 512-thread block
__global__ __launch_bounds__(512) void k_topscan(const unsigned* __restrict__ bsum,
                                                 unsigned* __restrict__ boff) {
    int t = threadIdx.x;
    unsigned v = (t < NBLK_SCAN) ? bsum[t] : 0u;
    __shared__ unsigned sm[512];
    sm[t] = v;
    __syncthreads();
    for (int o = 1; o < 512; o <<= 1) {
        unsigned u = (t >= o) ? sm[t - o] : 0u;
        __syncthreads();
        sm[t] += u;
        __syncthreads();
    }
    if (t < NBLK_SCAN) boff[t] = sm[t] - v;  // exclusive
}

// Scan phase 3: rowptr[i] = boff[blk] + exclusive_scan_within_block(deg)
__global__ __launch_bounds__(256) void k_scan3(const unsigned* __restrict__ deg,
                                               const unsigned* __restrict__ boff,
                                               unsigned* __restrict__ rowptr) {
    int t = threadIdx.x;
    int i = blockIdx.x * 256 + t;
    unsigned v = (i < NN) ? deg[i] : 0u;
    __shared__ unsigned sm[256];
    sm[t] = v;
    __syncthreads();
    for (int o = 1; o < 256; o <<= 1) {
        unsigned u = (t >= o) ? sm[t - o] : 0u;
        __syncthreads();
        sm[t] += u;
        __syncthreads();
    }
    unsigned incl = sm[t];
    if (i < NN) {
        rowptr[i] = boff[blockIdx.x] + incl - v;
        if (i == NN - 1) rowptr[NN] = boff[blockIdx.x] + incl;  // = NE
    }
}

// K5: bucket edges by target (counting sort): src[rowptr[c] + cursor[c]++] = row
__global__ __launch_bounds__(256) void k_bucket(const int* __restrict__ row,
                                                const int* __restrict__ col,
                                                const unsigned* __restrict__ rowptr,
                                                unsigned* __restrict__ cursor,
                                                unsigned* __restrict__ src) {
    int e = blockIdx.x * 256 + threadIdx.x;
    if (e >= NE) return;
    int c = col[e];
    unsigned p = rowptr[c] + atomicAdd(&cursor[c], 1u);
    src[p] = (unsigned)row[e];
}

// K6: atomic-free aggregate. One wave per node; lane owns features 2*lane, 2*lane+1.
// out[i] = (hs[i] + sum_{e in bucket(i)} hs[src[e]]) * dinv[i] + bias
__global__ __launch_bounds__(256) void k_agg(const float* __restrict__ hs,
                                             const unsigned* __restrict__ rowptr,
                                             const unsigned* __restrict__ src,
                                             const float* __restrict__ dinv,
                                             const float* __restrict__ bias,
                                             float* __restrict__ out) {
    int wave = threadIdx.x >> 6, lane = threadIdx.x & 63;
    int node = blockIdx.x * 4 + wave;
    if (node >= NN) return;
    int f = lane * 2;
    float2 acc = *(const float2*)(hs + (size_t)node * D + f);  // self loop
    unsigned s0 = rowptr[node], s1 = rowptr[node + 1];
    for (unsigned e = s0; e < s1; ++e) {
        unsigned r = src[e];
        float2 v = *(const float2*)(hs + (size_t)r * D + f);
        acc.x += v.x;
        acc.y += v.y;
    }
    float di = dinv[node];
    float2 b = *(const float2*)(bias + f);
    float2 o;
    o.x = fmaf(acc.x, di, b.x);
    o.y = fmaf(acc.y, di, b.y);
    *(float2*)(out + (size_t)node * D + f) = o;
}

extern "C" void kernel_launch(void* const* d_in, const int* in_sizes, int n_in,
                              void* d_out, int out_size, void* d_ws, size_t ws_size,
                              hipStream_t stream) {
    const float* x     = (const float*)d_in[0];
    const int*   ei    = (const int*)d_in[1];   // [2, NE] flat: row then col
    const float* gamma = (const float*)d_in[2];
    const float* beta  = (const float*)d_in[3];
    const float* W     = (const float*)d_in[4];
    const float* bias  = (const float*)d_in[5];
    float* out = (float*)d_out;

    const int* row = ei;
    const int* col = ei + NE;

    float* wsf = (float*)d_ws;
    float*    hs     = wsf + WS_HS;
    unsigned* deg    = (unsigned*)(wsf + WS_DEG);
    float*    dinv   = wsf + WS_DINV;
    unsigned* rowptr = (unsigned*)(wsf + WS_ROWPTR);
    unsigned* cursor = (unsigned*)(wsf + WS_CURSOR);
    unsigned* bsum   = (unsigned*)(wsf + WS_BSUM);
    unsigned* boff   = (unsigned*)(wsf + WS_BOFF);
    unsigned* srcb   = (unsigned*)(wsf + WS_SRC);

    hipMemsetAsync(deg,    0, NN * sizeof(unsigned), stream);
    hipMemsetAsync(cursor, 0, NN * sizeof(unsigned), stream);

    k_deg    <<<NE / 256,      256, 0, stream>>>(col, deg);
    k_dinv   <<<NBLK_SCAN,     256, 0, stream>>>(deg, dinv);
    k_ln     <<<NN / 4,        256, 0, stream>>>(x, gamma, beta, hs);
    k_gemm   <<<NN / 32,       256, 0, stream>>>(hs, W, dinv);
    k_sumblk <<<NBLK_SCAN,     256, 0, stream>>>(deg, bsum);
    k_topscan<<<1,             512, 0, stream>>>(bsum, boff);
    k_scan3  <<<NBLK_SCAN,     256, 0, stream>>>(deg, boff, rowptr);
    k_bucket <<<NE / 256,      256, 0, stream>>>(row, col, rowptr, cursor, srcb);
    k_agg    <<<NN / 4 + 1,    256, 0, stream>>>(hs, rowptr, srcb, dinv, bias, out);
}

// Round 7
// 454.891 us; speedup vs baseline: 3.5332x; 1.1981x over previous
//
#include <hip/hip_runtime.h>

#define NN 100000
#define NE 1600000
#define D 128
#define LN_EPS 1e-5f

// ---- workspace layout in 4-byte words (total 14,700,800 words = 58.8 MB) ----
#define WS_HS      0           // NN*D floats: hs = relu(LN(x)) @ W * dinv
#define WS_DEG     12800000    // NN u32
#define WS_CURSOR  12900000    // NN u32 (adjacent to deg -> one memset)
#define WS_ROWPTR  13000000    // NN+1 u32
#define WS_BSUM    13100004    // 391 u32
#define WS_BOFF    13100400    // 391 u32
#define WS_SRC     13100800    // NE u32
#define NBLK_SCAN  391         // ceil(NN/256)

__device__ __forceinline__ float f4_get(const float4& v, int kk) {
    return kk == 0 ? v.x : kk == 1 ? v.y : kk == 2 ? v.z : v.w;
}

// K1: degree histogram over targets (col)
__global__ __launch_bounds__(256) void k_deg(const int* __restrict__ col,
                                             unsigned* __restrict__ deg) {
    int e = blockIdx.x * 256 + threadIdx.x;
    if (e < NE) atomicAdd(&deg[col[e]], 1u);
}

// Scan phase 1: per-256-block sums of deg
__global__ __launch_bounds__(256) void k_sumblk(const unsigned* __restrict__ deg,
                                                unsigned* __restrict__ bsum) {
    int i = blockIdx.x * 256 + threadIdx.x;
    unsigned v = (i < NN) ? deg[i] : 0u;
    #pragma unroll
    for (int o = 32; o; o >>= 1) v += __shfl_xor(v, o);
    __shared__ unsigned sm[4];
    if ((threadIdx.x & 63) == 0) sm[threadIdx.x >> 6] = v;
    __syncthreads();
    if (threadIdx.x == 0)
        bsum[blockIdx.x] = sm[0] + sm[1] + sm[2] + sm[3];
}

// Scan phase 2: exclusive scan of bsum, one 512-thread block
__global__ __launch_bounds__(512) void k_topscan(const unsigned* __restrict__ bsum,
                                                 unsigned* __restrict__ boff) {
    int t = threadIdx.x;
    unsigned v = (t < NBLK_SCAN) ? bsum[t] : 0u;
    __shared__ unsigned sm[512];
    sm[t] = v;
    __syncthreads();
    for (int o = 1; o < 512; o <<= 1) {
        unsigned u = (t >= o) ? sm[t - o] : 0u;
        __syncthreads();
        sm[t] += u;
        __syncthreads();
    }
    if (t < NBLK_SCAN) boff[t] = sm[t] - v;  // exclusive
}

// Scan phase 3: rowptr[i] = boff[blk] + exclusive_scan_within_block(deg)
__global__ __launch_bounds__(256) void k_scan3(const unsigned* __restrict__ deg,
                                               const unsigned* __restrict__ boff,
                                               unsigned* __restrict__ rowptr) {
    int t = threadIdx.x;
    int i = blockIdx.x * 256 + t;
    unsigned v = (i < NN) ? deg[i] : 0u;
    __shared__ unsigned sm[256];
    sm[t] = v;
    __syncthreads();
    for (int o = 1; o < 256; o <<= 1) {
        unsigned u = (t >= o) ? sm[t - o] : 0u;
        __syncthreads();
        sm[t] += u;
        __syncthreads();
    }
    unsigned incl = sm[t];
    if (i < NN) {
        rowptr[i] = boff[blockIdx.x] + incl - v;
        if (i == NN - 1) rowptr[NN] = boff[blockIdx.x] + incl;  // = NE
    }
}

// K2: bucket edges by target (counting sort): src[rowptr[c] + cursor[c]++] = row
__global__ __launch_bounds__(256) void k_bucket(const int* __restrict__ row,
                                                const int* __restrict__ col,
                                                const unsigned* __restrict__ rowptr,
                                                unsigned* __restrict__ cursor,
                                                unsigned* __restrict__ src) {
    int e = blockIdx.x * 256 + threadIdx.x;
    if (e >= NE) return;
    int c = col[e];
    unsigned p = rowptr[c] + atomicAdd(&cursor[c], 1u);
    src[p] = (unsigned)row[e];
}

// K3: fused LayerNorm+ReLU -> LDS -> GEMM -> *dinv. 32 rows x 128 cols per block.
// LN: wave w normalizes rows 8w..8w+7 into As. GEMM: thread t computes
// rows mBase..+3 (mBase=(t>>5)*4) x cols cBase..+3 (cBase=(t&31)*4).
__global__ __launch_bounds__(256) void k_lngemm(const float* __restrict__ x,
                                                const float* __restrict__ gamma,
                                                const float* __restrict__ beta,
                                                const float* __restrict__ W,
                                                const unsigned* __restrict__ deg,
                                                float* __restrict__ hs) {
    __shared__ float As[32][128];
    int t = threadIdx.x;
    int wave = t >> 6, lane = t & 63;
    size_t rowBase = (size_t)blockIdx.x * 32;

    float g0 = gamma[lane], g1 = gamma[lane + 64];
    float b0 = beta[lane],  b1 = beta[lane + 64];
    #pragma unroll
    for (int rr = 0; rr < 8; ++rr) {
        int r = wave * 8 + rr;
        const float* xr = x + (rowBase + r) * D;
        float v0 = xr[lane], v1 = xr[lane + 64];
        float s = v0 + v1;
        #pragma unroll
        for (int o = 32; o; o >>= 1) s += __shfl_xor(s, o);
        float mu = s * (1.f / 128.f);
        float d0 = v0 - mu, d1 = v1 - mu;
        float q = d0 * d0 + d1 * d1;
        #pragma unroll
        for (int o = 32; o; o >>= 1) q += __shfl_xor(q, o);
        float rs = rsqrtf(q * (1.f / 128.f) + LN_EPS);
        As[r][lane]      = fmaxf(fmaf(d0 * rs, g0, b0), 0.f);
        As[r][lane + 64] = fmaxf(fmaf(d1 * rs, g1, b1), 0.f);
    }
    __syncthreads();

    int mBase = (t >> 5) * 4;
    int cBase = (t & 31) * 4;
    const float* Wp = W + cBase;
    float4 acc[4];
    #pragma unroll
    for (int i = 0; i < 4; ++i) acc[i] = make_float4(0.f, 0.f, 0.f, 0.f);

    for (int k = 0; k < D; k += 4) {
        float4 am[4];
        #pragma unroll
        for (int i = 0; i < 4; ++i)
            am[i] = *(const float4*)(&As[mBase + i][k]);
        #pragma unroll
        for (int kk = 0; kk < 4; ++kk) {
            float4 w4 = *(const float4*)(Wp + (size_t)(k + kk) * D);
            #pragma unroll
            for (int i = 0; i < 4; ++i) {
                float av = f4_get(am[i], kk);
                acc[i].x = fmaf(av, w4.x, acc[i].x);
                acc[i].y = fmaf(av, w4.y, acc[i].y);
                acc[i].z = fmaf(av, w4.z, acc[i].z);
                acc[i].w = fmaf(av, w4.w, acc[i].w);
            }
        }
    }
    #pragma unroll
    for (int i = 0; i < 4; ++i) {
        size_t r = rowBase + mBase + i;
        float dv = rsqrtf((float)(deg[r] + 1u));  // dinv inline
        float4 o;
        o.x = acc[i].x * dv; o.y = acc[i].y * dv;
        o.z = acc[i].z * dv; o.w = acc[i].w * dv;
        *(float4*)(hs + r * D + cBase) = o;
    }
}

// K4: atomic-free aggregate, 4 gathers in flight. One wave per node;
// lane owns features 2*lane, 2*lane+1.
// out[i] = (hs[i] + sum_e hs[src[e]]) * dinv[i] + bias
__global__ __launch_bounds__(256) void k_agg(const float* __restrict__ hs,
                                             const unsigned* __restrict__ rowptr,
                                             const unsigned* __restrict__ src,
                                             const float* __restrict__ bias,
                                             float* __restrict__ out) {
    int wave = threadIdx.x >> 6, lane = threadIdx.x & 63;
    int node = blockIdx.x * 4 + wave;
    if (node >= NN) return;
    int f = lane * 2;
    float2 acc = *(const float2*)(hs + (size_t)node * D + f);  // self loop
    unsigned s0 = rowptr[node], s1 = rowptr[node + 1];
    unsigned dg = s1 - s0;
    const unsigned* sp = src + s0;
    unsigned e = 0, n4 = dg & ~3u;
    for (; e < n4; e += 4) {
        unsigned r0 = sp[e], r1 = sp[e + 1], r2 = sp[e + 2], r3 = sp[e + 3];
        float2 v0 = *(const float2*)(hs + (size_t)r0 * D + f);
        float2 v1 = *(const float2*)(hs + (size_t)r1 * D + f);
        float2 v2 = *(const float2*)(hs + (size_t)r2 * D + f);
        float2 v3 = *(const float2*)(hs + (size_t)r3 * D + f);
        acc.x += (v0.x + v1.x) + (v2.x + v3.x);
        acc.y += (v0.y + v1.y) + (v2.y + v3.y);
    }
    for (; e < dg; ++e) {
        unsigned r = sp[e];
        float2 v = *(const float2*)(hs + (size_t)r * D + f);
        acc.x += v.x;
        acc.y += v.y;
    }
    float di = rsqrtf((float)(dg + 1u));
    float2 b = *(const float2*)(bias + f);
    float2 o;
    o.x = fmaf(acc.x, di, b.x);
    o.y = fmaf(acc.y, di, b.y);
    *(float2*)(out + (size_t)node * D + f) = o;
}

extern "C" void kernel_launch(void* const* d_in, const int* in_sizes, int n_in,
                              void* d_out, int out_size, void* d_ws, size_t ws_size,
                              hipStream_t stream) {
    const float* x     = (const float*)d_in[0];
    const int*   ei    = (const int*)d_in[1];   // [2, NE] flat: row then col
    const float* gamma = (const float*)d_in[2];
    const float* beta  = (const float*)d_in[3];
    const float* W     = (const float*)d_in[4];
    const float* bias  = (const float*)d_in[5];
    float* out = (float*)d_out;

    const int* row = ei;
    const int* col = ei + NE;

    float* wsf = (float*)d_ws;
    float*    hs     = wsf + WS_HS;
    unsigned* deg    = (unsigned*)(wsf + WS_DEG);
    unsigned* cursor = (unsigned*)(wsf + WS_CURSOR);
    unsigned* rowptr = (unsigned*)(wsf + WS_ROWPTR);
    unsigned* bsum   = (unsigned*)(wsf + WS_BSUM);
    unsigned* boff   = (unsigned*)(wsf + WS_BOFF);
    unsigned* srcb   = (unsigned*)(wsf + WS_SRC);

    // deg and cursor are adjacent: one memset clears both
    hipMemsetAsync(deg, 0, 2u * NN * sizeof(unsigned), stream);

    k_deg    <<<NE / 256,  256, 0, stream>>>(col, deg);
    k_sumblk <<<NBLK_SCAN, 256, 0, stream>>>(deg, bsum);
    k_topscan<<<1,         512, 0, stream>>>(bsum, boff);
    k_scan3  <<<NBLK_SCAN, 256, 0, stream>>>(deg, boff, rowptr);
    k_bucket <<<NE / 256,  256, 0, stream>>>(row, col, rowptr, cursor, srcb);
    k_lngemm <<<NN / 32,   256, 0, stream>>>(x, gamma, beta, W, deg, hs);
    k_agg    <<<NN / 4,    256, 0, stream>>>(hs, rowptr, srcb, bias, out);
}

// Round 12
// 376.737 us; speedup vs baseline: 4.2661x; 1.2075x over previous
//
#include <hip/hip_runtime.h>

#define NN 100000
#define NE 1600000
#define D 128
#define LN_EPS 1e-5f

// ---- workspace layout in 4-byte words (total 14,700,800 words = 58.8 MB) ----
#define WS_HS      0           // NN*D floats: hs = relu(LN(x)) @ W * dinv
                               // (first 400K words double as pos[NE] u8 before k_lngemm)
#define WS_DEG     12800000    // NN u32
#define WS_ROWPTR  13000000    // NN+1 u32
#define WS_BSUM    13100004    // 391 u32
#define WS_BOFF    13100400    // 391 u32
#define WS_SRC     13100800    // NE u32
#define NBLK_SCAN  391         // ceil(NN/256)

__device__ __forceinline__ float f4_get(const float4& v, int kk) {
    return kk == 0 ? v.x : kk == 1 ? v.y : kk == 2 ? v.z : v.w;
}

// K1: degree histogram over targets + capture within-bucket position (u8).
// 4 edges/thread for memory-level parallelism.
__global__ __launch_bounds__(256) void k_deg(const int* __restrict__ col,
                                             unsigned* __restrict__ deg,
                                             unsigned char* __restrict__ pos) {
    int e4 = (blockIdx.x * 256 + threadIdx.x) * 4;
    if (e4 >= NE) return;
    int4 c4 = *(const int4*)(col + e4);
    unsigned p0 = atomicAdd(&deg[c4.x], 1u);
    unsigned p1 = atomicAdd(&deg[c4.y], 1u);
    unsigned p2 = atomicAdd(&deg[c4.z], 1u);
    unsigned p3 = atomicAdd(&deg[c4.w], 1u);
    uchar4 pk;
    pk.x = (unsigned char)p0; pk.y = (unsigned char)p1;
    pk.z = (unsigned char)p2; pk.w = (unsigned char)p3;
    *(uchar4*)(pos + e4) = pk;
}

// Scan phase 1: per-256-block sums of deg
__global__ __launch_bounds__(256) void k_sumblk(const unsigned* __restrict__ deg,
                                                unsigned* __restrict__ bsum) {
    int i = blockIdx.x * 256 + threadIdx.x;
    unsigned v = (i < NN) ? deg[i] : 0u;
    #pragma unroll
    for (int o = 32; o; o >>= 1) v += __shfl_xor(v, o);
    __shared__ unsigned sm[4];
    if ((threadIdx.x & 63) == 0) sm[threadIdx.x >> 6] = v;
    __syncthreads();
    if (threadIdx.x == 0)
        bsum[blockIdx.x] = sm[0] + sm[1] + sm[2] + sm[3];
}

// Scan phase 2: exclusive scan of bsum, one 512-thread block
__global__ __launch_bounds__(512) void k_topscan(const unsigned* __restrict__ bsum,
                                                 unsigned* __restrict__ boff) {
    int t = threadIdx.x;
    unsigned v = (t < NBLK_SCAN) ? bsum[t] : 0u;
    __shared__ unsigned sm[512];
    sm[t] = v;
    __syncthreads();
    for (int o = 1; o < 512; o <<= 1) {
        unsigned u = (t >= o) ? sm[t - o] : 0u;
        __syncthreads();
        sm[t] += u;
        __syncthreads();
    }
    if (t < NBLK_SCAN) boff[t] = sm[t] - v;  // exclusive
}

// Scan phase 3: rowptr[i] = boff[blk] + exclusive_scan_within_block(deg)
__global__ __launch_bounds__(256) void k_scan3(const unsigned* __restrict__ deg,
                                               const unsigned* __restrict__ boff,
                                               unsigned* __restrict__ rowptr) {
    int t = threadIdx.x;
    int i = blockIdx.x * 256 + t;
    unsigned v = (i < NN) ? deg[i] : 0u;
    __shared__ unsigned sm[256];
    sm[t] = v;
    __syncthreads();
    for (int o = 1; o < 256; o <<= 1) {
        unsigned u = (t >= o) ? sm[t - o] : 0u;
        __syncthreads();
        sm[t] += u;
        __syncthreads();
    }
    unsigned incl = sm[t];
    if (i < NN) {
        rowptr[i] = boff[blockIdx.x] + incl - v;
        if (i == NN - 1) rowptr[NN] = boff[blockIdx.x] + incl;  // = NE
    }
}

// K2: atomic-free bucket scatter: src[rowptr[c] + pos[e]] = row[e].
// 4 edges/thread for MLP.
__global__ __launch_bounds__(256) void k_bucket(const int* __restrict__ row,
                                                const int* __restrict__ col,
                                                const unsigned* __restrict__ rowptr,
                                                const unsigned char* __restrict__ pos,
                                                unsigned* __restrict__ src) {
    int e4 = (blockIdx.x * 256 + threadIdx.x) * 4;
    if (e4 >= NE) return;
    int4 c4 = *(const int4*)(col + e4);
    int4 r4 = *(const int4*)(row + e4);
    uchar4 p4 = *(const uchar4*)(pos + e4);
    unsigned b0 = rowptr[c4.x];
    unsigned b1 = rowptr[c4.y];
    unsigned b2 = rowptr[c4.z];
    unsigned b3 = rowptr[c4.w];
    src[b0 + p4.x] = (unsigned)r4.x;
    src[b1 + p4.y] = (unsigned)r4.y;
    src[b2 + p4.z] = (unsigned)r4.z;
    src[b3 + p4.w] = (unsigned)r4.w;
}

// K3: fused LayerNorm+ReLU -> LDS -> GEMM -> *dinv. 32 rows x 128 cols per block.
__global__ __launch_bounds__(256) void k_lngemm(const float* __restrict__ x,
                                                const float* __restrict__ gamma,
                                                const float* __restrict__ beta,
                                                const float* __restrict__ W,
                                                const unsigned* __restrict__ deg,
                                                float* __restrict__ hs) {
    __shared__ float As[32][128];
    int t = threadIdx.x;
    int wave = t >> 6, lane = t & 63;
    size_t rowBase = (size_t)blockIdx.x * 32;

    float g0 = gamma[lane], g1 = gamma[lane + 64];
    float b0 = beta[lane],  b1 = beta[lane + 64];
    #pragma unroll
    for (int rr = 0; rr < 8; ++rr) {
        int r = wave * 8 + rr;
        const float* xr = x + (rowBase + r) * D;
        float v0 = xr[lane], v1 = xr[lane + 64];
        float s = v0 + v1;
        #pragma unroll
        for (int o = 32; o; o >>= 1) s += __shfl_xor(s, o);
        float mu = s * (1.f / 128.f);
        float d0 = v0 - mu, d1 = v1 - mu;
        float q = d0 * d0 + d1 * d1;
        #pragma unroll
        for (int o = 32; o; o >>= 1) q += __shfl_xor(q, o);
        float rs = rsqrtf(q * (1.f / 128.f) + LN_EPS);
        As[r][lane]      = fmaxf(fmaf(d0 * rs, g0, b0), 0.f);
        As[r][lane + 64] = fmaxf(fmaf(d1 * rs, g1, b1), 0.f);
    }
    __syncthreads();

    int mBase = (t >> 5) * 4;
    int cBase = (t & 31) * 4;
    const float* Wp = W + cBase;
    float4 acc[4];
    #pragma unroll
    for (int i = 0; i < 4; ++i) acc[i] = make_float4(0.f, 0.f, 0.f, 0.f);

    for (int k = 0; k < D; k += 4) {
        float4 am[4];
        #pragma unroll
        for (int i = 0; i < 4; ++i)
            am[i] = *(const float4*)(&As[mBase + i][k]);
        #pragma unroll
        for (int kk = 0; kk < 4; ++kk) {
            float4 w4 = *(const float4*)(Wp + (size_t)(k + kk) * D);
            #pragma unroll
            for (int i = 0; i < 4; ++i) {
                float av = f4_get(am[i], kk);
                acc[i].x = fmaf(av, w4.x, acc[i].x);
                acc[i].y = fmaf(av, w4.y, acc[i].y);
                acc[i].z = fmaf(av, w4.z, acc[i].z);
                acc[i].w = fmaf(av, w4.w, acc[i].w);
            }
        }
    }
    #pragma unroll
    for (int i = 0; i < 4; ++i) {
        size_t r = rowBase + mBase + i;
        float dv = rsqrtf((float)(deg[r] + 1u));  // dinv inline
        float4 o;
        o.x = acc[i].x * dv; o.y = acc[i].y * dv;
        o.z = acc[i].z * dv; o.w = acc[i].w * dv;
        *(float4*)(hs + r * D + cBase) = o;
    }
}

// K4: atomic-free aggregate, 4 gathers in flight. One wave per node;
// lane owns features 2*lane, 2*lane+1.
__global__ __launch_bounds__(256) void k_agg(const float* __restrict__ hs,
                                             const unsigned* __restrict__ rowptr,
                                             const unsigned* __restrict__ src,
                                             const float* __restrict__ bias,
                                             float* __restrict__ out) {
    int wave = threadIdx.x >> 6, lane = threadIdx.x & 63;
    int node = blockIdx.x * 4 + wave;
    if (node >= NN) return;
    int f = lane * 2;
    float2 acc = *(const float2*)(hs + (size_t)node * D + f);  // self loop
    unsigned s0 = rowptr[node], s1 = rowptr[node + 1];
    unsigned dg = s1 - s0;
    const unsigned* sp = src + s0;
    unsigned e = 0, n4 = dg & ~3u;
    for (; e < n4; e += 4) {
        unsigned r0 = sp[e], r1 = sp[e + 1], r2 = sp[e + 2], r3 = sp[e + 3];
        float2 v0 = *(const float2*)(hs + (size_t)r0 * D + f);
        float2 v1 = *(const float2*)(hs + (size_t)r1 * D + f);
        float2 v2 = *(const float2*)(hs + (size_t)r2 * D + f);
        float2 v3 = *(const float2*)(hs + (size_t)r3 * D + f);
        acc.x += (v0.x + v1.x) + (v2.x + v3.x);
        acc.y += (v0.y + v1.y) + (v2.y + v3.y);
    }
    for (; e < dg; ++e) {
        unsigned r = sp[e];
        float2 v = *(const float2*)(hs + (size_t)r * D + f);
        acc.x += v.x;
        acc.y += v.y;
    }
    float di = rsqrtf((float)(dg + 1u));
    float2 b = *(const float2*)(bias + f);
    float2 o;
    o.x = fmaf(acc.x, di, b.x);
    o.y = fmaf(acc.y, di, b.y);
    *(float2*)(out + (size_t)node * D + f) = o;
}

extern "C" void kernel_launch(void* const* d_in, const int* in_sizes, int n_in,
                              void* d_out, int out_size, void* d_ws, size_t ws_size,
                              hipStream_t stream) {
    const float* x     = (const float*)d_in[0];
    const int*   ei    = (const int*)d_in[1];   // [2, NE] flat: row then col
    const float* gamma = (const float*)d_in[2];
    const float* beta  = (const float*)d_in[3];
    const float* W     = (const float*)d_in[4];
    const float* bias  = (const float*)d_in[5];
    float* out = (float*)d_out;

    const int* row = ei;
    const int* col = ei + NE;

    float* wsf = (float*)d_ws;
    float*         hs     = wsf + WS_HS;
    unsigned char* pos    = (unsigned char*)(wsf + WS_HS);  // hs prefix, pre-k_lngemm only
    unsigned*      deg    = (unsigned*)(wsf + WS_DEG);
    unsigned*      rowptr = (unsigned*)(wsf + WS_ROWPTR);
    unsigned*      bsum   = (unsigned*)(wsf + WS_BSUM);
    unsigned*      boff   = (unsigned*)(wsf + WS_BOFF);
    unsigned*      srcb   = (unsigned*)(wsf + WS_SRC);

    hipMemsetAsync(deg, 0, NN * sizeof(unsigned), stream);

    const int EB = (NE / 4 + 255) / 256;  // 4 edges/thread blocks
    k_deg    <<<EB,        256, 0, stream>>>(col, deg, pos);
    k_sumblk <<<NBLK_SCAN, 256, 0, stream>>>(deg, bsum);
    k_topscan<<<1,         512, 0, stream>>>(bsum, boff);
    k_scan3  <<<NBLK_SCAN, 256, 0, stream>>>(deg, boff, rowptr);
    k_bucket <<<EB,        256, 0, stream>>>(row, col, rowptr, pos, srcb);
    k_lngemm <<<NN / 32,   256, 0, stream>>>(x, gamma, beta, W, deg, hs);
    k_agg    <<<NN / 4,    256, 0, stream>>>(hs, rowptr, srcb, bias, out);
}

// Round 14
// 334.372 us; speedup vs baseline: 4.8066x; 1.1267x over previous
//
#include <hip/hip_runtime.h>

#define NN 100000
#define NE 1600000
#define D 128
#define LN_EPS 1e-5f

// ---- workspace layout in 4-byte words (total 14,700,800 words = 58.8 MB) ----
#define WS_HS      0           // NN*D bf16 (6.4M words used; region reserved 12.8M)
                               // (first 400K words double as pos[NE] u8 before k_lngemm)
#define WS_DEG     12800000    // NN u32
#define WS_ROWPTR  13000000    // NN+1 u32
#define WS_BSUM    13100004    // 391 u32
#define WS_BOFF    13100400    // 391 u32
#define WS_SRC     13100800    // NE u32
#define NBLK_SCAN  391         // ceil(NN/256)

__device__ __forceinline__ float f4_get(const float4& v, int kk) {
    return kk == 0 ? v.x : kk == 1 ? v.y : kk == 2 ? v.z : v.w;
}

// round-to-nearest-even f32 -> bf16 bits
__device__ __forceinline__ unsigned short f2bf(float f) {
    unsigned u = __float_as_uint(f);
    u += 0x7FFFu + ((u >> 16) & 1u);
    return (unsigned short)(u >> 16);
}
__device__ __forceinline__ float bf2f(unsigned short h) {
    return __uint_as_float(((unsigned)h) << 16);
}

// K1: degree histogram over targets + capture within-bucket position (u8).
__global__ __launch_bounds__(256) void k_deg(const int* __restrict__ col,
                                             unsigned* __restrict__ deg,
                                             unsigned char* __restrict__ pos) {
    int e4 = (blockIdx.x * 256 + threadIdx.x) * 4;
    if (e4 >= NE) return;
    int4 c4 = *(const int4*)(col + e4);
    unsigned p0 = atomicAdd(&deg[c4.x], 1u);
    unsigned p1 = atomicAdd(&deg[c4.y], 1u);
    unsigned p2 = atomicAdd(&deg[c4.z], 1u);
    unsigned p3 = atomicAdd(&deg[c4.w], 1u);
    uchar4 pk;
    pk.x = (unsigned char)p0; pk.y = (unsigned char)p1;
    pk.z = (unsigned char)p2; pk.w = (unsigned char)p3;
    *(uchar4*)(pos + e4) = pk;
}

// Scan phase 1: per-256-block sums of deg
__global__ __launch_bounds__(256) void k_sumblk(const unsigned* __restrict__ deg,
                                                unsigned* __restrict__ bsum) {
    int i = blockIdx.x * 256 + threadIdx.x;
    unsigned v = (i < NN) ? deg[i] : 0u;
    #pragma unroll
    for (int o = 32; o; o >>= 1) v += __shfl_xor(v, o);
    __shared__ unsigned sm[4];
    if ((threadIdx.x & 63) == 0) sm[threadIdx.x >> 6] = v;
    __syncthreads();
    if (threadIdx.x == 0)
        bsum[blockIdx.x] = sm[0] + sm[1] + sm[2] + sm[3];
}

// Scan phase 2: exclusive scan of bsum, one 512-thread block
__global__ __launch_bounds__(512) void k_topscan(const unsigned* __restrict__ bsum,
                                                 unsigned* __restrict__ boff) {
    int t = threadIdx.x;
    unsigned v = (t < NBLK_SCAN) ? bsum[t] : 0u;
    __shared__ unsigned sm[512];
    sm[t] = v;
    __syncthreads();
    for (int o = 1; o < 512; o <<= 1) {
        unsigned u = (t >= o) ? sm[t - o] : 0u;
        __syncthreads();
        sm[t] += u;
        __syncthreads();
    }
    if (t < NBLK_SCAN) boff[t] = sm[t] - v;  // exclusive
}

// Scan phase 3: rowptr[i] = boff[blk] + exclusive_scan_within_block(deg)
__global__ __launch_bounds__(256) void k_scan3(const unsigned* __restrict__ deg,
                                               const unsigned* __restrict__ boff,
                                               unsigned* __restrict__ rowptr) {
    int t = threadIdx.x;
    int i = blockIdx.x * 256 + t;
    unsigned v = (i < NN) ? deg[i] : 0u;
    __shared__ unsigned sm[256];
    sm[t] = v;
    __syncthreads();
    for (int o = 1; o < 256; o <<= 1) {
        unsigned u = (t >= o) ? sm[t - o] : 0u;
        __syncthreads();
        sm[t] += u;
        __syncthreads();
    }
    unsigned incl = sm[t];
    if (i < NN) {
        rowptr[i] = boff[blockIdx.x] + incl - v;
        if (i == NN - 1) rowptr[NN] = boff[blockIdx.x] + incl;  // = NE
    }
}

// K2: atomic-free bucket scatter: src[rowptr[c] + pos[e]] = row[e].
__global__ __launch_bounds__(256) void k_bucket(const int* __restrict__ row,
                                                const int* __restrict__ col,
                                                const unsigned* __restrict__ rowptr,
                                                const unsigned char* __restrict__ pos,
                                                unsigned* __restrict__ src) {
    int e4 = (blockIdx.x * 256 + threadIdx.x) * 4;
    if (e4 >= NE) return;
    int4 c4 = *(const int4*)(col + e4);
    int4 r4 = *(const int4*)(row + e4);
    uchar4 p4 = *(const uchar4*)(pos + e4);
    unsigned b0 = rowptr[c4.x];
    unsigned b1 = rowptr[c4.y];
    unsigned b2 = rowptr[c4.z];
    unsigned b3 = rowptr[c4.w];
    src[b0 + p4.x] = (unsigned)r4.x;
    src[b1 + p4.y] = (unsigned)r4.y;
    src[b2 + p4.z] = (unsigned)r4.z;
    src[b3 + p4.w] = (unsigned)r4.w;
}

// K3: fused LayerNorm+ReLU -> LDS -> GEMM -> *dinv -> bf16 store.
__global__ __launch_bounds__(256) void k_lngemm(const float* __restrict__ x,
                                                const float* __restrict__ gamma,
                                                const float* __restrict__ beta,
                                                const float* __restrict__ W,
                                                const unsigned* __restrict__ deg,
                                                unsigned short* __restrict__ hsb) {
    __shared__ float As[32][128];
    int t = threadIdx.x;
    int wave = t >> 6, lane = t & 63;
    size_t rowBase = (size_t)blockIdx.x * 32;

    float g0 = gamma[lane], g1 = gamma[lane + 64];
    float b0 = beta[lane],  b1 = beta[lane + 64];
    #pragma unroll
    for (int rr = 0; rr < 8; ++rr) {
        int r = wave * 8 + rr;
        const float* xr = x + (rowBase + r) * D;
        float v0 = xr[lane], v1 = xr[lane + 64];
        float s = v0 + v1;
        #pragma unroll
        for (int o = 32; o; o >>= 1) s += __shfl_xor(s, o);
        float mu = s * (1.f / 128.f);
        float d0 = v0 - mu, d1 = v1 - mu;
        float q = d0 * d0 + d1 * d1;
        #pragma unroll
        for (int o = 32; o; o >>= 1) q += __shfl_xor(q, o);
        float rs = rsqrtf(q * (1.f / 128.f) + LN_EPS);
        As[r][lane]      = fmaxf(fmaf(d0 * rs, g0, b0), 0.f);
        As[r][lane + 64] = fmaxf(fmaf(d1 * rs, g1, b1), 0.f);
    }
    __syncthreads();

    int mBase = (t >> 5) * 4;
    int cBase = (t & 31) * 4;
    const float* Wp = W + cBase;
    float4 acc[4];
    #pragma unroll
    for (int i = 0; i < 4; ++i) acc[i] = make_float4(0.f, 0.f, 0.f, 0.f);

    for (int k = 0; k < D; k += 4) {
        float4 am[4];
        #pragma unroll
        for (int i = 0; i < 4; ++i)
            am[i] = *(const float4*)(&As[mBase + i][k]);
        #pragma unroll
        for (int kk = 0; kk < 4; ++kk) {
            float4 w4 = *(const float4*)(Wp + (size_t)(k + kk) * D);
            #pragma unroll
            for (int i = 0; i < 4; ++i) {
                float av = f4_get(am[i], kk);
                acc[i].x = fmaf(av, w4.x, acc[i].x);
                acc[i].y = fmaf(av, w4.y, acc[i].y);
                acc[i].z = fmaf(av, w4.z, acc[i].z);
                acc[i].w = fmaf(av, w4.w, acc[i].w);
            }
        }
    }
    #pragma unroll
    for (int i = 0; i < 4; ++i) {
        size_t r = rowBase + mBase + i;
        float dv = rsqrtf((float)(deg[r] + 1u));  // dinv inline
        ushort4 o;
        o.x = f2bf(acc[i].x * dv);
        o.y = f2bf(acc[i].y * dv);
        o.z = f2bf(acc[i].z * dv);
        o.w = f2bf(acc[i].w * dv);
        *(ushort4*)(hsb + r * D + cBase) = o;  // 8 B store
    }
}

// K4: atomic-free aggregate over bf16 hs, 8 gathers in flight.
// One wave per node; lane owns features 2*lane, 2*lane+1 (one u32 per row).
__global__ __launch_bounds__(256) void k_agg(const unsigned short* __restrict__ hsb,
                                             const unsigned* __restrict__ rowptr,
                                             const unsigned* __restrict__ src,
                                             const float* __restrict__ bias,
                                             float* __restrict__ out) {
    int wave = threadIdx.x >> 6, lane = threadIdx.x & 63;
    int node = blockIdx.x * 4 + wave;
    if (node >= NN) return;
    int f = lane * 2;
    unsigned sv = *(const unsigned*)(hsb + (size_t)node * D + f);  // self loop
    float ax = bf2f((unsigned short)(sv & 0xFFFFu));
    float ay = bf2f((unsigned short)(sv >> 16));
    unsigned s0 = rowptr[node], s1 = rowptr[node + 1];
    unsigned dg = s1 - s0;
    const unsigned* sp = src + s0;
    unsigned e = 0, n8 = dg & ~7u;
    for (; e < n8; e += 8) {
        unsigned v0 = *(const unsigned*)(hsb + (size_t)sp[e]     * D + f);
        unsigned v1 = *(const unsigned*)(hsb + (size_t)sp[e + 1] * D + f);
        unsigned v2 = *(const unsigned*)(hsb + (size_t)sp[e + 2] * D + f);
        unsigned v3 = *(const unsigned*)(hsb + (size_t)sp[e + 3] * D + f);
        unsigned v4 = *(const unsigned*)(hsb + (size_t)sp[e + 4] * D + f);
        unsigned v5 = *(const unsigned*)(hsb + (size_t)sp[e + 5] * D + f);
        unsigned v6 = *(const unsigned*)(hsb + (size_t)sp[e + 6] * D + f);
        unsigned v7 = *(const unsigned*)(hsb + (size_t)sp[e + 7] * D + f);
        ax += bf2f((unsigned short)(v0 & 0xFFFFu)) + bf2f((unsigned short)(v1 & 0xFFFFu))
            + bf2f((unsigned short)(v2 & 0xFFFFu)) + bf2f((unsigned short)(v3 & 0xFFFFu))
            + bf2f((unsigned short)(v4 & 0xFFFFu)) + bf2f((unsigned short)(v5 & 0xFFFFu))
            + bf2f((unsigned short)(v6 & 0xFFFFu)) + bf2f((unsigned short)(v7 & 0xFFFFu));
        ay += bf2f((unsigned short)(v0 >> 16)) + bf2f((unsigned short)(v1 >> 16))
            + bf2f((unsigned short)(v2 >> 16)) + bf2f((unsigned short)(v3 >> 16))
            + bf2f((unsigned short)(v4 >> 16)) + bf2f((unsigned short)(v5 >> 16))
            + bf2f((unsigned short)(v6 >> 16)) + bf2f((unsigned short)(v7 >> 16));
    }
    for (; e < dg; ++e) {
        unsigned v = *(const unsigned*)(hsb + (size_t)sp[e] * D + f);
        ax += bf2f((unsigned short)(v & 0xFFFFu));
        ay += bf2f((unsigned short)(v >> 16));
    }
    float di = rsqrtf((float)(dg + 1u));
    float2 b = *(const float2*)(bias + f);
    float2 o;
    o.x = fmaf(ax, di, b.x);
    o.y = fmaf(ay, di, b.y);
    *(float2*)(out + (size_t)node * D + f) = o;
}

extern "C" void kernel_launch(void* const* d_in, const int* in_sizes, int n_in,
                              void* d_out, int out_size, void* d_ws, size_t ws_size,
                              hipStream_t stream) {
    const float* x     = (const float*)d_in[0];
    const int*   ei    = (const int*)d_in[1];   // [2, NE] flat: row then col
    const float* gamma = (const float*)d_in[2];
    const float* beta  = (const float*)d_in[3];
    const float* W     = (const float*)d_in[4];
    const float* bias  = (const float*)d_in[5];
    float* out = (float*)d_out;

    const int* row = ei;
    const int* col = ei + NE;

    float* wsf = (float*)d_ws;
    unsigned short* hsb   = (unsigned short*)(wsf + WS_HS);
    unsigned char*  pos   = (unsigned char*)(wsf + WS_HS);  // aliases hs; consumed pre-k_lngemm
    unsigned*       deg   = (unsigned*)(wsf + WS_DEG);
    unsigned*       rowptr= (unsigned*)(wsf + WS_ROWPTR);
    unsigned*       bsum  = (unsigned*)(wsf + WS_BSUM);
    unsigned*       boff  = (unsigned*)(wsf + WS_BOFF);
    unsigned*       srcb  = (unsigned*)(wsf + WS_SRC);

    hipMemsetAsync(deg, 0, NN * sizeof(unsigned), stream);

    const int EB = (NE / 4 + 255) / 256;  // 4 edges/thread blocks
    k_deg    <<<EB,        256, 0, stream>>>(col, deg, pos);
    k_sumblk <<<NBLK_SCAN, 256, 0, stream>>>(deg, bsum);
    k_topscan<<<1,         512, 0, stream>>>(bsum, boff);
    k_scan3  <<<NBLK_SCAN, 256, 0, stream>>>(deg, boff, rowptr);
    k_bucket <<<EB,        256, 0, stream>>>(row, col, rowptr, pos, srcb);
    k_lngemm <<<NN / 32,   256, 0, stream>>>(x, gamma, beta, W, deg, hsb);
    k_agg    <<<NN / 4,    256, 0, stream>>>(hsb, rowptr, srcb, bias, out);
}